// Round 5
// baseline (163.456 us; speedup 1.0000x reference)
//
#include <hip/hip_runtime.h>

// Problem constants
#define B_   64
#define M_   256
#define D_   256
#define A_   18
#define E_   4
#define S_   64
#define ES_  256          // E_*S_ == M_
#define H_   512
#define K2_  (A_*D_)      // 4608

typedef _Float16 f16;
typedef _Float16 f16x4 __attribute__((ext_vector_type(4)));
typedef _Float16 f16x8 __attribute__((ext_vector_type(8)));
typedef float    f32x4 __attribute__((ext_vector_type(4)));

// ===========================================================================
// fp32 src [z][R][C] -> fp16 dst [z][C][R]  (transpose + convert) — weights
// ===========================================================================
__global__ __launch_bounds__(256) void k_tcvt(
    const float* __restrict__ src, f16* __restrict__ dst,
    int R, int C, long sbs, long dbs)
{
  __shared__ f16 T[64][68];
  const int t = threadIdx.x;
  const int rr = t >> 4, cc = (t & 15) * 4;
  const int r0 = blockIdx.y * 64, c0 = blockIdx.x * 64;
  src += (long)blockIdx.z * sbs;
  dst += (long)blockIdx.z * dbs;
#pragma unroll
  for (int p = 0; p < 4; ++p) {
    const int row = rr + p * 16;
    const float4 v = *reinterpret_cast<const float4*>(
        &src[(long)(r0 + row) * C + c0 + cc]);
    T[row][cc + 0] = (f16)v.x; T[row][cc + 1] = (f16)v.y;
    T[row][cc + 2] = (f16)v.z; T[row][cc + 3] = (f16)v.w;
  }
  __syncthreads();
#pragma unroll
  for (int p = 0; p < 4; ++p) {
    const int oc = rr + p * 16;
    f16x4 g;
#pragma unroll
    for (int i = 0; i < 4; ++i) g[i] = T[cc + i][oc];
    *reinterpret_cast<f16x4*>(&dst[(long)(c0 + oc) * R + r0 + cc]) = g;
  }
}

// ===========================================================================
// MFMA GEMM core (f16 operands, K-contiguous both sides), 64x64 tile,
// 256 threads = 4 waves in 2x2; OUT_MODE: 0 f16 [M][N], 1 f16 [N][M], 2 f32.
// ===========================================================================
template<int RELU, int HAS_BIAS, int OUT_MODE>
__device__ __forceinline__ void mfma_gemm(
    const f16* __restrict__ A, int lda,
    const f16* __restrict__ BT, int ldb,
    const float* __restrict__ bias,
    void* __restrict__ Cout, int ldc, int K)
{
  const int t    = threadIdx.x;
  const int w    = t >> 6, lane = t & 63;
  const int wr   = w >> 1, wc = w & 1;
  const int m0   = blockIdx.y * 64 + wr * 32;
  const int n0   = blockIdx.x * 64 + wc * 32;
  const int lr   = lane & 15;
  const int lk   = (lane >> 4) * 8;

  f32x4 acc00 = {}, acc01 = {}, acc10 = {}, acc11 = {};
  const f16* Ap = A  + (long)(m0 + lr) * lda + lk;
  const f16* Bp = BT + (long)(n0 + lr) * ldb + lk;

  for (int k0 = 0; k0 < K; k0 += 32) {
    const f16x8 a0 = *reinterpret_cast<const f16x8*>(Ap);
    const f16x8 a1 = *reinterpret_cast<const f16x8*>(Ap + (long)16 * lda);
    const f16x8 b0 = *reinterpret_cast<const f16x8*>(Bp);
    const f16x8 b1 = *reinterpret_cast<const f16x8*>(Bp + (long)16 * ldb);
    acc00 = __builtin_amdgcn_mfma_f32_16x16x32_f16(a0, b0, acc00, 0, 0, 0);
    acc01 = __builtin_amdgcn_mfma_f32_16x16x32_f16(a0, b1, acc01, 0, 0, 0);
    acc10 = __builtin_amdgcn_mfma_f32_16x16x32_f16(a1, b0, acc10, 0, 0, 0);
    acc11 = __builtin_amdgcn_mfma_f32_16x16x32_f16(a1, b1, acc11, 0, 0, 0);
    Ap += 32; Bp += 32;
  }

  const int orow = (lane >> 4) * 4;
  f32x4 accs[2][2] = {{acc00, acc01}, {acc10, acc11}};
#pragma unroll
  for (int fi = 0; fi < 2; ++fi) {
#pragma unroll
    for (int fj = 0; fj < 2; ++fj) {
      const int gm = m0 + fi * 16 + orow;
      const int gn = n0 + fj * 16 + lr;
      f32x4 v = accs[fi][fj];
      if (HAS_BIAS) {
        const float bv = bias[gn];
        v[0] += bv; v[1] += bv; v[2] += bv; v[3] += bv;
      }
      if (RELU) {
#pragma unroll
        for (int r = 0; r < 4; ++r) v[r] = fmaxf(v[r], 0.f);
      }
      if (OUT_MODE == 0) {
        f16* C = (f16*)Cout;
#pragma unroll
        for (int r = 0; r < 4; ++r) C[(long)(gm + r) * ldc + gn] = (f16)v[r];
      } else if (OUT_MODE == 1) {
        f16x4 h4; h4[0] = (f16)v[0]; h4[1] = (f16)v[1];
        h4[2] = (f16)v[2]; h4[3] = (f16)v[3];
        *reinterpret_cast<f16x4*>(&((f16*)Cout)[(long)gn * ldc + gm]) = h4;
      } else {
        float* C = (float*)Cout;
#pragma unroll
        for (int r = 0; r < 4; ++r) C[(long)(gm + r) * ldc + gn] = v[r];
      }
    }
  }
}

// ===========================================================================
// k_logits: logits16[b][m][es] = obs_fp32[b] @ phi_fp32  (both converted
// in-kernel; phi staged transposed in LDS once per block)
// grid (4 es, 4 m, 64 b), 256 threads
// ===========================================================================
__global__ __launch_bounds__(256) void k_logits(
    const float* __restrict__ obs, const float* __restrict__ phi,
    f16* __restrict__ logits16)
{
  __shared__ f16 Bs[64][264];   // [es_local][d], stride 264 -> 2-way banks
  const int t = threadIdx.x;
  const int es0 = blockIdx.x * 64, m0b = blockIdx.y * 64;
  const long bo = (long)blockIdx.z * (M_ * D_);

  {  // stage phi^T tile: Bs[es][d] from phi[d][es]
    const int el = t & 63, wg = t >> 6;
    for (int dp = 0; dp < D_; dp += 32) {
      f16x8 hv;
#pragma unroll
      for (int j = 0; j < 8; ++j)
        hv[j] = (f16)phi[(long)(dp + wg * 8 + j) * ES_ + es0 + el];
      *reinterpret_cast<f16x8*>(&Bs[el][dp + wg * 8]) = hv;
    }
  }
  __syncthreads();

  const int w = t >> 6, lane = t & 63;
  const int wr = w >> 1, wc = w & 1;
  const int m0 = m0b + wr * 32;
  const int lr = lane & 15, lk = (lane >> 4) * 8;
  f32x4 acc[2][2] = {};

  for (int k0 = 0; k0 < D_; k0 += 32) {
    f16x8 af[2], bf[2];
#pragma unroll
    for (int fi = 0; fi < 2; ++fi) {
      const float* ap = &obs[bo + (long)(m0 + fi * 16 + lr) * D_ + k0 + lk];
      const float4 u0 = *reinterpret_cast<const float4*>(ap);
      const float4 u1 = *reinterpret_cast<const float4*>(ap + 4);
      f16x8 a;
      a[0] = (f16)u0.x; a[1] = (f16)u0.y; a[2] = (f16)u0.z; a[3] = (f16)u0.w;
      a[4] = (f16)u1.x; a[5] = (f16)u1.y; a[6] = (f16)u1.z; a[7] = (f16)u1.w;
      af[fi] = a;
    }
#pragma unroll
    for (int fj = 0; fj < 2; ++fj)
      bf[fj] = *reinterpret_cast<const f16x8*>(&Bs[wc * 32 + fj * 16 + lr][k0 + lk]);
#pragma unroll
    for (int fi = 0; fi < 2; ++fi)
#pragma unroll
      for (int fj = 0; fj < 2; ++fj)
        acc[fi][fj] = __builtin_amdgcn_mfma_f32_16x16x32_f16(
            af[fi], bf[fj], acc[fi][fj], 0, 0, 0);
  }

  const int orow = (lane >> 4) * 4;
  f16* C = logits16 + (long)blockIdx.z * (M_ * ES_);
#pragma unroll
  for (int fi = 0; fi < 2; ++fi)
#pragma unroll
    for (int fj = 0; fj < 2; ++fj) {
      const int gm = m0 + fi * 16 + orow;
      const int gn = es0 + wc * 32 + fj * 16 + lr;
#pragma unroll
      for (int r = 0; r < 4; ++r)
        C[(long)(gm + r) * ES_ + gn] = (f16)acc[fi][fj][r];
    }
}

// ===========================================================================
// k_dispatchT: softmax over tokens m + transposed write dispT[b][es][m].
// LDS-caches the 256x64 logits slice so global is read ONCE.
// grid (4 es, 64 b), 256 threads
// ===========================================================================
__global__ __launch_bounds__(256) void k_dispatchT(
    const f16* __restrict__ logits16, f16* __restrict__ dispT16)
{
  __shared__ f16 cache[256][66];   // stride 66 -> column reads 2-way (free)
  __shared__ float smx[4][64], ssm[4][64], cmax[64], cinv[64];
  const int t = threadIdx.x, x = t & 63, g = t >> 6;
  const int es0 = blockIdx.x * 64;
  const long bb = (long)blockIdx.y * (M_ * ES_);

  float mx = -1e30f, sm = 0.f;
  for (int m = g; m < M_; m += 4) {
    const f16 hv = logits16[bb + (long)m * ES_ + es0 + x];
    cache[m][x] = hv;
    const float v = (float)hv;
    const float nm = fmaxf(mx, v);
    sm = sm * __expf(mx - nm) + __expf(v - nm);
    mx = nm;
  }
  smx[g][x] = mx; ssm[g][x] = sm;
  __syncthreads();
  if (t < 64) {
    float M0 = smx[0][t], S0 = ssm[0][t];
#pragma unroll
    for (int i = 1; i < 4; ++i) {
      const float Mi = smx[i][t], Si = ssm[i][t];
      const float nm = fmaxf(M0, Mi);
      S0 = S0 * __expf(M0 - nm) + Si * __expf(Mi - nm);
      M0 = nm;
    }
    cmax[t] = M0; cinv[t] = 1.0f / S0;
  }
  __syncthreads();

  // phase 2: each wave walks es rows; reads LDS column, writes coalesced
  const int lane = t & 63, w = t >> 6;
  for (int el = w; el < 64; el += 4) {
    const float M0 = cmax[el], inv = cinv[el];
#pragma unroll
    for (int mc = 0; mc < 4; ++mc) {
      const int m = mc * 64 + lane;
      const float v = (float)cache[m][el];
      dispT16[bb + (long)(es0 + el) * M_ + m] = (f16)(__expf(v - M0) * inv);
    }
  }
}

// ===========================================================================
// k_combine: softmax over all ES slots per (b,m) row
// ===========================================================================
__global__ __launch_bounds__(256) void k_combine(
    const f16* __restrict__ logits16, f16* __restrict__ comb16)
{
  const int t = threadIdx.x;
  const int lane = t & 63, wv = t >> 6;
  const long row = (long)blockIdx.x * 4 + wv;
  const f16x4 v = *reinterpret_cast<const f16x4*>(&logits16[row * ES_ + lane * 4]);
  float f0 = (float)v[0], f1 = (float)v[1], f2 = (float)v[2], f3 = (float)v[3];
  float mx = fmaxf(fmaxf(f0, f1), fmaxf(f2, f3));
#pragma unroll
  for (int o = 32; o; o >>= 1) mx = fmaxf(mx, __shfl_xor(mx, o));
  const float e0 = __expf(f0 - mx), e1 = __expf(f1 - mx);
  const float e2 = __expf(f2 - mx), e3 = __expf(f3 - mx);
  float sm = e0 + e1 + e2 + e3;
#pragma unroll
  for (int o = 32; o; o >>= 1) sm += __shfl_xor(sm, o);
  const float inv = 1.0f / sm;
  f16x4 r; r[0] = (f16)(e0 * inv); r[1] = (f16)(e1 * inv);
  r[2] = (f16)(e2 * inv); r[3] = (f16)(e3 * inv);
  *reinterpret_cast<f16x4*>(&comb16[row * ES_ + lane * 4]) = r;
}

// ===========================================================================
// k_slots: slots16[b][es][d] = dispT16[b] @ obs_fp32[b]  (K = m)
// A direct from dispT (K-contig); B staged per k-tile: obs fp32 rows ->
// f16x8 pack -> single ds_write_b128 per thread per tile.
// grid (4 d, 4 es, 64 b), 256 threads
// ===========================================================================
__global__ __launch_bounds__(256) void k_slots(
    const f16* __restrict__ dispT16, const float* __restrict__ obs,
    f16* __restrict__ slots16)
{
  __shared__ f16 Bs[64][40];   // [d_local][m_tile 32 + pad]
  const int t = threadIdx.x;
  const int d0 = blockIdx.x * 64, es0 = blockIdx.y * 64;
  const long bb = (long)blockIdx.z * (ES_ * M_);
  const long bo = (long)blockIdx.z * (M_ * D_);
  const int w = t >> 6, lane = t & 63;
  const int wr = w >> 1, wc = w & 1;
  const int lr = lane & 15, lk = (lane >> 4) * 8;
  const int dl = t & 63, wg = t >> 6;

  f32x4 acc[2][2] = {};
  const f16* Ap = dispT16 + bb + (long)(es0 + wr * 32 + lr) * M_ + lk;

  for (int k0 = 0; k0 < M_; k0 += 32) {
    f16x8 hv;
#pragma unroll
    for (int j = 0; j < 8; ++j)
      hv[j] = (f16)obs[bo + (long)(k0 + wg * 8 + j) * D_ + d0 + dl];
    __syncthreads();           // previous tile fully consumed
    *reinterpret_cast<f16x8*>(&Bs[dl][wg * 8]) = hv;
    __syncthreads();

    f16x8 af[2], bf[2];
#pragma unroll
    for (int fi = 0; fi < 2; ++fi)
      af[fi] = *reinterpret_cast<const f16x8*>(Ap + (long)fi * 16 * M_ + k0);
#pragma unroll
    for (int fj = 0; fj < 2; ++fj)
      bf[fj] = *reinterpret_cast<const f16x8*>(&Bs[wc * 32 + fj * 16 + lr][lk]);
#pragma unroll
    for (int fi = 0; fi < 2; ++fi)
#pragma unroll
      for (int fj = 0; fj < 2; ++fj)
        acc[fi][fj] = __builtin_amdgcn_mfma_f32_16x16x32_f16(
            af[fi], bf[fj], acc[fi][fj], 0, 0, 0);
  }

  const int orow = (lane >> 4) * 4;
  f16* C = slots16 + (long)blockIdx.z * (ES_ * D_);
#pragma unroll
  for (int fi = 0; fi < 2; ++fi)
#pragma unroll
    for (int fj = 0; fj < 2; ++fj) {
      const int gm = es0 + wr * 32 + fi * 16 + orow;
      const int gn = d0 + wc * 32 + fj * 16 + lr;
#pragma unroll
      for (int r = 0; r < 4; ++r)
        C[(long)(gm + r) * D_ + gn] = (f16)acc[fi][fj][r];
    }
}

// ---- k_h: h16[z][s][h] = relu(slots16[b,e] @ w1T[e]^T + b1[e]) ------------
__global__ __launch_bounds__(256) void k_h(
    const f16* __restrict__ slots16, const f16* __restrict__ w1T,
    const float* __restrict__ b1, f16* __restrict__ h16)
{
  const long z = blockIdx.z; const long e = z & 3;
  mfma_gemm<1, 1, 0>(slots16 + z * (S_ * D_), D_,
                     w1T + e * (H_ * D_), D_,
                     b1 + e * H_,
                     h16 + z * (S_ * H_), H_, D_);
}

// ---- k_y: yT16[b][d][es] = (h16[b,e] @ w2T[e, a-slice]^T + b2) transposed -
__global__ __launch_bounds__(256) void k_y(
    const f16* __restrict__ h16, const f16* __restrict__ w2T,
    const float* __restrict__ b2, const int* __restrict__ action,
    f16* __restrict__ yT16)
{
  const long z = blockIdx.z; const long b = z >> 2, e = z & 3;
  int a = action[b];
  a = (a < 0) ? 0 : (a >= A_ ? A_ - 1 : a);
  mfma_gemm<0, 1, 1>(h16 + z * (S_ * H_), H_,
                     w2T + e * ((long)K2_ * H_) + (long)a * D_ * H_, H_,
                     b2 + e * K2_ + a * D_,
                     yT16 + b * (D_ * ES_) + e * S_, ES_, H_);
}

// ---- k_out: out[b][m][d] (fp32) = comb16[b] @ yT16[b]^T  (K = es) ---------
__global__ __launch_bounds__(256) void k_out(
    const f16* __restrict__ comb16, const f16* __restrict__ yT16,
    float* __restrict__ out)
{
  const long b = blockIdx.z;
  mfma_gemm<0, 0, 2>(comb16 + b * (M_ * ES_), ES_, yT16 + b * (D_ * ES_), ES_,
                     nullptr, out + b * (M_ * D_), D_, ES_);
}

// ===========================================================================
extern "C" void kernel_launch(void* const* d_in, const int* in_sizes, int n_in,
                              void* d_out, int out_size, void* d_ws, size_t ws_size,
                              hipStream_t stream)
{
  const float* obs    = (const float*)d_in[0];
  const int*   action = (const int*)d_in[1];
  const float* phi    = (const float*)d_in[2];
  const float* w1     = (const float*)d_in[3];
  const float* b1     = (const float*)d_in[4];
  const float* w2     = (const float*)d_in[5];
  const float* b2     = (const float*)d_in[6];
  float*       out    = (float*)d_out;

  // Workspace (f16 units), total 78.6 MB
  f16* ws = (f16*)d_ws;
  f16* w1T      = ws + 0;          //   524,288
  f16* w2T      = ws + 524288;     // 9,437,184
  f16* logits16 = ws + 9961472;    // 4,194,304
  f16* dispT16  = ws + 14155776;   // 4,194,304
  f16* comb16   = ws + 18350080;   // 4,194,304
  f16* slots16  = ws + 22544384;   // 4,194,304
  f16* h16      = ws + 26738688;   // 8,388,608
  f16* yT16     = ws + 35127296;   // 4,194,304

  // one-time weight conversions
  k_tcvt<<<dim3(8, 4, 4),  256, 0, stream>>>(w1, w1T, D_, H_,
                                             (long)D_ * H_, (long)H_ * D_);
  k_tcvt<<<dim3(72, 8, 4), 256, 0, stream>>>(w2, w2T, H_, K2_,
                                             (long)H_ * K2_, (long)K2_ * H_);
  // pipeline
  k_logits   <<<dim3(4, 4, 64), 256, 0, stream>>>(obs, phi, logits16);
  k_dispatchT<<<dim3(4, 64),    256, 0, stream>>>(logits16, dispT16);
  k_combine  <<<dim3(4096),     256, 0, stream>>>(logits16, comb16);
  k_slots    <<<dim3(4, 4, 64), 256, 0, stream>>>(dispT16, obs, slots16);
  k_h        <<<dim3(8, 1, 256),256, 0, stream>>>(slots16, w1T, b1, h16);
  k_y        <<<dim3(4, 1, 256),256, 0, stream>>>(h16, w2T, b2, action, yT16);
  k_out      <<<dim3(4, 4, 64), 256, 0, stream>>>(comb16, yT16, out);
}